// Round 3
// baseline (8250.597 us; speedup 1.0000x reference)
//
#include <hip/hip_runtime.h>
#include <stdint.h>

#define H 1024
#define G_ 256
#define LPAD 128

typedef float  floatx4 __attribute__((ext_vector_type(4)));
typedef short  shortx8 __attribute__((ext_vector_type(8)));

#define MFMA(a, b, c) __builtin_amdgcn_mfma_f32_16x16x32_bf16((a), (b), (c), 0, 0, 0)

__device__ __forceinline__ uint16_t f2bf(float f) {
  union { float f; uint32_t i; } v; v.f = f;
  uint32_t r = (v.i + 0x7FFFu + ((v.i >> 16) & 1u)) >> 16;
  return (uint16_t)r;
}
__device__ __forceinline__ float bf2f(uint16_t u) {
  union { uint32_t i; float f; } v; v.i = ((uint32_t)u) << 16; return v.f;
}
__device__ __forceinline__ float sigmoid_(float x) { return 1.f / (1.f + __expf(-x)); }
__device__ __forceinline__ float tanh_(float x) {
  float ax = fabsf(x);
  float e = __expf(2.f * ax);          // overflow -> inf -> t = 1 (correct limit)
  float t = 1.f - 2.f / (e + 1.f);
  return x >= 0.f ? t : -t;
}

// ---------------- fp32 -> bf16 cast, 8 elems/thread ----------------
__global__ void k_f2b(const float* __restrict__ src, uint16_t* __restrict__ dst) {
  size_t i = ((size_t)blockIdx.x * blockDim.x + threadIdx.x) * 8;
  float4 a = *(const float4*)(src + i);
  float4 b = *(const float4*)(src + i + 4);
  uint16_t o[8] = {f2bf(a.x), f2bf(a.y), f2bf(a.z), f2bf(a.w),
                   f2bf(b.x), f2bf(b.y), f2bf(b.z), f2bf(b.w)};
  uint4 ov; __builtin_memcpy(&ov, o, 16);
  *(uint4*)(dst + i) = ov;
}

// ---------------- setup: start[g] via binary search over sorted batch ----------------
__global__ void k_setup(const int* __restrict__ batch, int N, int* __restrict__ start) {
  int g = threadIdx.x;
  if (g > G_) return;
  int lo = 0, hi = N;
  while (lo < hi) { int mid = (lo + hi) >> 1; if (batch[mid] < g) lo = mid + 1; else hi = mid; }
  start[g] = lo;
}

// ---------------- message = relu(h_atom + bias) -> bf16 ----------------
__global__ void k_msg(const float* __restrict__ h_atom, const float* __restrict__ bias,
                      uint16_t* __restrict__ msg) {
  int row = blockIdx.x, t = threadIdx.x;           // 128 threads * 8 elems
  size_t off = (size_t)row * H + t * 8;
  float4 h0 = *(const float4*)(h_atom + off);
  float4 h1 = *(const float4*)(h_atom + off + 4);
  float4 b0 = *(const float4*)(bias + t * 8);
  float4 b1 = *(const float4*)(bias + t * 8 + 4);
  float v[8] = {h0.x + b0.x, h0.y + b0.y, h0.z + b0.z, h0.w + b0.w,
                h1.x + b1.x, h1.y + b1.y, h1.z + b1.z, h1.w + b1.w};
  uint16_t o[8];
#pragma unroll
  for (int i = 0; i < 8; i++) o[i] = f2bf(v[i] > 0.f ? v[i] : 0.f);
  uint4 ov; __builtin_memcpy(&ov, o, 16);
  *(uint4*)(msg + off) = ov;
}

// ---------------- h0 = segment_max(h_atom); write fp32 + bf16, both dirs (buf 0) --------
__global__ void k_h0(const float* __restrict__ h_atom, const int* __restrict__ start,
                     float* __restrict__ hf32, uint16_t* __restrict__ hbf) {
  int g = blockIdx.x, t = threadIdx.x;             // 256 threads * 4 cols
  int s = start[g], e = start[g + 1];
  float m[4] = {-INFINITY, -INFINITY, -INFINITY, -INFINITY};
  const float* base = h_atom + t * 4;
  for (int a = s; a < e; a++) {
    float4 v = *(const float4*)(base + (size_t)a * H);
    m[0] = fmaxf(m[0], v.x); m[1] = fmaxf(m[1], v.y);
    m[2] = fmaxf(m[2], v.z); m[3] = fmaxf(m[3], v.w);
  }
  if (s == e) { m[0] = m[1] = m[2] = m[3] = 0.f; }
#pragma unroll
  for (int i = 0; i < 4; i++) {
    int c = t * 4 + i;
    float mv = m[i];
    uint16_t bv = f2bf(mv);
    // layout: [(dir*2 + buf)][G][H]; buf 0 for both dirs
    hf32[(size_t)0 * G_ * H + (size_t)g * H + c] = mv;
    hf32[(size_t)2 * G_ * H + (size_t)g * H + c] = mv;
    hbf [(size_t)0 * G_ * H + (size_t)g * H + c] = bv;
    hbf [(size_t)2 * G_ * H + (size_t)g * H + c] = bv;
  }
}

// ---------------- xg = msg @ [Wf; Wb]^T  -> (N, 6144) bf16 ----------------
// 128x128 tile, BK=64, 4 waves 2x2, 16x16x32 MFMA, register-staged LDS.
__global__ __launch_bounds__(256) void k_gemm_xg(
    const uint16_t* __restrict__ A, const uint16_t* __restrict__ Wf,
    const uint16_t* __restrict__ Wb, uint16_t* __restrict__ C, int N) {
  __shared__ __align__(16) uint16_t As[128 * 64];
  __shared__ __align__(16) uint16_t Bs[128 * 64];
  int bn = blockIdx.x, bm = blockIdx.y;            // bn 0..47, bm 0..N/128-1
  const uint16_t* B = (bn < 24) ? Wf : Wb;
  int brow = (bn < 24 ? bn : bn - 24) * 128;
  int tid = threadIdx.x, wid = tid >> 6, lane = tid & 63;
  int wm = wid >> 1, wn = wid & 1;
  floatx4 acc[4][4];
#pragma unroll
  for (int mi = 0; mi < 4; mi++)
#pragma unroll
    for (int ni = 0; ni < 4; ni++) acc[mi][ni] = (floatx4){0.f, 0.f, 0.f, 0.f};
  int arow = bm * 128;
  for (int kb = 0; kb < H; kb += 64) {
    uint4 av[4], bv[4];
#pragma unroll
    for (int p = 0; p < 4; p++) {                  // chunk c: row c>>3, k-off (c&7)*8
      int c = p * 256 + tid;
      av[p] = *(const uint4*)(A + (size_t)(arow + (c >> 3)) * H + kb + (c & 7) * 8);
      bv[p] = *(const uint4*)(B + (size_t)(brow + (c >> 3)) * H + kb + (c & 7) * 8);
    }
    __syncthreads();                               // prior iter's LDS reads done
#pragma unroll
    for (int p = 0; p < 4; p++) {
      int c = p * 256 + tid;
      *(uint4*)(As + (size_t)c * 8) = av[p];
      *(uint4*)(Bs + (size_t)c * 8) = bv[p];
    }
    __syncthreads();
#pragma unroll
    for (int ks = 0; ks < 2; ks++) {
      const uint16_t* ab = As + ((wm * 64 + (lane & 15)) * 64 + ks * 32 + (lane >> 4) * 8);
      const uint16_t* bb = Bs + ((wn * 64 + (lane & 15)) * 64 + ks * 32 + (lane >> 4) * 8);
      shortx8 af[4], bfr[4];
#pragma unroll
      for (int i = 0; i < 4; i++) {
        af[i]  = *(const shortx8*)(ab + i * 16 * 64);
        bfr[i] = *(const shortx8*)(bb + i * 16 * 64);
      }
#pragma unroll
      for (int mi = 0; mi < 4; mi++)
#pragma unroll
        for (int ni = 0; ni < 4; ni++)
          acc[mi][ni] = MFMA(af[mi], bfr[ni], acc[mi][ni]);
    }
  }
  // C/D layout: col = lane&15, row = (lane>>4)*4 + r  [m89-verified]
  int colb = bn * 128 + wn * 64 + (lane & 15);
  int rowb = bm * 128 + wm * 64 + (lane >> 4) * 4;
#pragma unroll
  for (int mi = 0; mi < 4; mi++)
#pragma unroll
    for (int ni = 0; ni < 4; ni++) {
      size_t base = (size_t)(rowb + mi * 16) * 6144 + colb + ni * 16;
#pragma unroll
      for (int r = 0; r < 4; r++) C[base + (size_t)r * 6144] = f2bf(acc[mi][ni][r]);
    }
}

// ---------------- one GRU time step, both directions fused ----------------
// grid = 256 wgs: b&7 encodes (dir, j%4) -> XCD slot for L2 weight affinity.
// wg owns (64 g-rows) x (32 h-cols) with the (r,z,n) weight-row triple: 64x96 GEMM, K=1024.
__global__ __launch_bounds__(256) void k_step(
    int l, const uint16_t* __restrict__ xg,
    const uint16_t* __restrict__ whf, const uint16_t* __restrict__ whb,
    const float* __restrict__ bihf, const float* __restrict__ bhhf,
    const float* __restrict__ bihb, const float* __restrict__ bhhb,
    float* __restrict__ hf32, uint16_t* __restrict__ hbf,
    const int* __restrict__ start, float* __restrict__ out) {
  __shared__ __align__(16) uint16_t As[64 * 64];
  __shared__ __align__(16) uint16_t Bs[96 * 64];
  __shared__ float HG[64 * 97];                    // stride 97: gate reads <=2-way banks
  int b = blockIdx.x;
  int e = b & 7, hi = b >> 3;
  int d = e >> 2, jm = e & 3;
  int jc = (hi & 7) * 4 + jm;                      // 0..31 (32-col chunk within H)
  int g0 = (hi >> 3) * 64;
  int cur = l & 1;
  const uint16_t* W = d ? whb : whf;
  const uint16_t* hsrc = hbf + (size_t)(d * 2 + cur) * G_ * H;
  int tid = threadIdx.x, wid = tid >> 6, lane = tid & 63;
  int wm = wid >> 1, wn = wid & 1;                 // waves 2x2 over (64 x 96) -> 32x48 tiles
  floatx4 acc[2][3];
#pragma unroll
  for (int mi = 0; mi < 2; mi++)
#pragma unroll
    for (int ni = 0; ni < 3; ni++) acc[mi][ni] = (floatx4){0.f, 0.f, 0.f, 0.f};

  for (int kb = 0; kb < H; kb += 64) {
    uint4 av[2], bv[3];
#pragma unroll
    for (int p = 0; p < 2; p++) {                  // A: 64x64 bf16, 512 chunks
      int c = p * 256 + tid;
      av[p] = *(const uint4*)(hsrc + (size_t)(g0 + (c >> 3)) * H + kb + (c & 7) * 8);
    }
#pragma unroll
    for (int p = 0; p < 3; p++) {                  // B: 96x64 bf16 (r,z,n weight rows)
      int c = p * 256 + tid;
      int row = c >> 3;
      int wrow = (row >> 5) * H + jc * 32 + (row & 31);
      bv[p] = *(const uint4*)(W + (size_t)wrow * H + kb + (c & 7) * 8);
    }
    __syncthreads();
#pragma unroll
    for (int p = 0; p < 2; p++) *(uint4*)(As + (size_t)(p * 256 + tid) * 8) = av[p];
#pragma unroll
    for (int p = 0; p < 3; p++) *(uint4*)(Bs + (size_t)(p * 256 + tid) * 8) = bv[p];
    __syncthreads();
#pragma unroll
    for (int ks = 0; ks < 2; ks++) {
      const uint16_t* ab = As + ((wm * 32 + (lane & 15)) * 64 + ks * 32 + (lane >> 4) * 8);
      const uint16_t* bb = Bs + ((wn * 48 + (lane & 15)) * 64 + ks * 32 + (lane >> 4) * 8);
      shortx8 a0 = *(const shortx8*)ab;
      shortx8 a1 = *(const shortx8*)(ab + 16 * 64);
#pragma unroll
      for (int ni = 0; ni < 3; ni++) {
        shortx8 bvf = *(const shortx8*)(bb + ni * 16 * 64);
        acc[0][ni] = MFMA(a0, bvf, acc[0][ni]);
        acc[1][ni] = MFMA(a1, bvf, acc[1][ni]);
      }
    }
  }
  __syncthreads();                                 // last MFMA ds_reads done before HG reuse
  // spill hg (64x96) to LDS for the gate-triple exchange
#pragma unroll
  for (int mi = 0; mi < 2; mi++)
#pragma unroll
    for (int ni = 0; ni < 3; ni++) {
      int row0 = wm * 32 + mi * 16 + (lane >> 4) * 4;
      int col = wn * 48 + ni * 16 + (lane & 15);
#pragma unroll
      for (int r = 0; r < 4; r++) HG[(row0 + r) * 97 + col] = acc[mi][ni][r];
    }
  __syncthreads();

  // gates: 64*32 = 2048 h-elems, 8 per thread
  int base = tid * 8;
  int gl = base >> 5, j0 = base & 31;
  int g = g0 + gl;
  int s = start[g], cnt = start[g + 1] - s;
  int t = d ? (LPAD - 1 - l) : l;
  bool active = (t < cnt);                         // padded steps: xt = b_ih (msg == 0)
  int col0 = jc * 32 + j0;
  const float* bih = d ? bihb : bihf;
  const float* bhh = d ? bhhb : bhhf;
  const uint16_t* xp = xg + (size_t)(s + t) * 6144 + (size_t)d * 3072;  // deref iff active
  const float* h_old = hf32 + ((size_t)(d * 2 + cur) * G_ + g) * H + col0;
  float* h_new32 = hf32 + ((size_t)(d * 2 + (cur ^ 1)) * G_ + g) * H + col0;
  uint16_t* h_newb = hbf + ((size_t)(d * 2 + (cur ^ 1)) * G_ + g) * H + col0;
  float* op = out + (size_t)(s + t) * 2048 + (size_t)d * H + col0;
#pragma unroll
  for (int i = 0; i < 8; i++) {
    int c = col0 + i;
    float hr = HG[gl * 97 + j0 + i];
    float hz = HG[gl * 97 + 32 + j0 + i];
    float hn = HG[gl * 97 + 64 + j0 + i];
    float xr = 0.f, xz = 0.f, xn = 0.f;
    if (active) { xr = bf2f(xp[c]); xz = bf2f(xp[H + c]); xn = bf2f(xp[2 * H + c]); }
    float r = sigmoid_(xr + bih[c] + hr + bhh[c]);
    float z = sigmoid_(xz + bih[H + c] + hz + bhh[H + c]);
    float n = tanh_(xn + bih[2 * H + c] + r * (hn + bhh[2 * H + c]));
    float hv = h_old[i];
    float hnew = (1.f - z) * n + z * hv;
    h_new32[i] = hnew;
    h_newb[i] = f2bf(hnew);
    if (active) op[i] = hnew;
  }
}

extern "C" void kernel_launch(void* const* d_in, const int* in_sizes, int n_in,
                              void* d_out, int out_size, void* d_ws, size_t ws_size,
                              hipStream_t stream) {
  const float* h_atom = (const float*)d_in[0];
  const int*   batch  = (const int*)d_in[1];
  const float* bias   = (const float*)d_in[2];
  const float* w_ih_f = (const float*)d_in[3];
  const float* w_hh_f = (const float*)d_in[4];
  const float* b_ih_f = (const float*)d_in[5];
  const float* b_hh_f = (const float*)d_in[6];
  const float* w_ih_b = (const float*)d_in[7];
  const float* w_hh_b = (const float*)d_in[8];
  const float* b_ih_b = (const float*)d_in[9];
  const float* b_hh_b = (const float*)d_in[10];
  int N = in_sizes[0] / H;                          // 16384
  float* out = (float*)d_out;

  const size_t W3 = (size_t)3 * H * H;              // 3.1M elems per weight
  char* ws = (char*)d_ws;
  uint16_t* msg  = (uint16_t*)ws;                           // N*H bf16
  uint16_t* xg   = (uint16_t*)(ws + (size_t)N * H * 2);     // N*6144 bf16
  char* p = ws + (size_t)N * H * 2 + (size_t)N * 6144 * 2;
  uint16_t* wihf = (uint16_t*)p; p += W3 * 2;
  uint16_t* wihb = (uint16_t*)p; p += W3 * 2;
  uint16_t* whhf = (uint16_t*)p; p += W3 * 2;
  uint16_t* whhb = (uint16_t*)p; p += W3 * 2;
  float*    hf32 = (float*)p;    p += (size_t)4 * G_ * H * 4;  // [dir][buf][G][H]
  uint16_t* hbf  = (uint16_t*)p; p += (size_t)4 * G_ * H * 2;
  int*      start = (int*)p;                                   // 257 ints

  int wgrid = (int)(W3 / (256 * 8));                // 1536
  k_f2b<<<wgrid, 256, 0, stream>>>(w_ih_f, wihf);
  k_f2b<<<wgrid, 256, 0, stream>>>(w_ih_b, wihb);
  k_f2b<<<wgrid, 256, 0, stream>>>(w_hh_f, whhf);
  k_f2b<<<wgrid, 256, 0, stream>>>(w_hh_b, whhb);
  k_setup<<<1, 512, 0, stream>>>(batch, N, start);
  k_msg<<<N, 128, 0, stream>>>(h_atom, bias, msg);
  k_h0<<<G_, 256, 0, stream>>>(h_atom, start, hf32, hbf);
  k_gemm_xg<<<dim3(48, N / 128), 256, 0, stream>>>(msg, wihf, wihb, xg, N);
  for (int l = 0; l < LPAD; l++)
    k_step<<<256, 256, 0, stream>>>(l, xg, whhf, whhb, b_ih_f, b_hh_f,
                                    b_ih_b, b_hh_b, hf32, hbf, start, out);
}